// Round 4
// baseline (329.548 us; speedup 1.0000x reference)
//
#include <hip/hip_runtime.h>

#define K1N 10
#define K2N 10
#define MMN 50

typedef __attribute__((ext_vector_type(8))) short short8;
typedef __attribute__((ext_vector_type(4))) float f32x4;

__device__ __forceinline__ float fast_tanh(float x) {
  x = fminf(fmaxf(x, -15.f), 15.f);
  float e2 = __expf(2.f * x);
  return (e2 - 1.f) * __builtin_amdgcn_rcpf(e2 + 1.f);
}

// reference's _avg_on_real_neighbor weight; exact div so cnt=0 -> w=1e8 -> 0
__device__ __forceinline__ float nb_w(float cnt) {
  float w = 1.0f / (cnt + 1e-8f);
  return (w >= 1e8f) ? 0.f : w;
}

// f32 -> bf16 RNE as raw ushort; exact bf16 -> f32
__device__ __forceinline__ unsigned short f2bf(float x) {
  unsigned u = __builtin_bit_cast(unsigned, x);
  return (unsigned short)((u + 0x7FFFu + ((u >> 16) & 1u)) >> 16);
}
__device__ __forceinline__ float bf2f(unsigned short s) {
  return __builtin_bit_cast(float, ((unsigned)s) << 16);
}

// ================= phase 1: block=4 waves, wave=4 elems, rows = 4bi x 4k =================
// Y[16x64] = X1*W21^T + X2*W22^T via mfma_f32_16x16x32_bf16, 3-term bf16 split.
// W21-hi B-frags in regs; W21-lo/W22-hi/W22-lo as swizzled bf16 LDS planes.
// X: one 2-plane (hi/lo) 4KB buffer per wave, time-shared between t1 and t2 passes.
__global__ __launch_bounds__(256, 4) void hgnn_phase1(
    const int* __restrict__ dsd1, const int* __restrict__ dsd2,
    const float* __restrict__ symp, const float* __restrict__ dise,
    const float* __restrict__ W21, const float* __restrict__ W22,
    float* __restrict__ s1avg) {
  __shared__ unsigned short Wl[3][4096];    // {w21lo, w22hi, w22lo}, [e][d] bf16, chunk-swizzled
  __shared__ unsigned short Xs[4][2][1024]; // per-wave [hi/lo][16 rows x 64]
  const int tid = threadIdx.x;
  const int lane = tid & 63;
  const int wv = __builtin_amdgcn_readfirstlane(tid >> 6);
  const int g = lane >> 4, r15 = lane & 15;

  // ---- stage 3 W planes: 1536 16B-chunks, 6 per thread, coalesced 32B global reads ----
#pragma unroll
  for (int i = 0; i < 6; ++i) {
    int c = tid + (i << 8);
    int pl = c >> 9;            // 0:w21lo 1:w22hi 2:w22lo
    int rc = c & 511;
    int row = rc >> 3, ch = rc & 7;
    const float* src = (pl == 0 ? W21 : W22) + row * 64 + ch * 8;
    short8 v;
#pragma unroll
    for (int j = 0; j < 8; ++j) {
      float w = src[j];
      unsigned short h = f2bf(w);
      v[j] = (short)((pl == 1) ? h : f2bf(w - bf2f(h)));
    }
    *reinterpret_cast<short8*>(&Wl[pl][row * 64 + ((ch ^ (row & 7)) << 3)]) = v;
  }
  // ---- W21-hi B-frags into 32 VGPRs ----
  short8 Bh[4][2];
#pragma unroll
  for (int nt = 0; nt < 4; ++nt)
#pragma unroll
    for (int ks = 0; ks < 2; ++ks) {
      const float4* p = reinterpret_cast<const float4*>(W21 + (nt * 16 + r15) * 64 + ks * 32 + g * 8);
      float4 va = p[0], vb = p[1];
      short8 h;
      h[0] = (short)f2bf(va.x); h[1] = (short)f2bf(va.y);
      h[2] = (short)f2bf(va.z); h[3] = (short)f2bf(va.w);
      h[4] = (short)f2bf(vb.x); h[5] = (short)f2bf(vb.y);
      h[6] = (short)f2bf(vb.z); h[7] = (short)f2bf(vb.w);
      Bh[nt][ks] = h;
    }
  __syncthreads();

  const int b0w = blockIdx.x * 16 + wv * 4;
  unsigned short* x0 = &Xs[wv][0][0];
  unsigned short* x1p = &Xs[wv][1][0];
  float s1sum[4] = {0.f, 0.f, 0.f, 0.f};
  float c1f = 0.f;

#define P1_STEP(KBASE, KQ)                                                         \
  {                                                                                \
    float t2r[4][KQ];                                                              \
    _Pragma("unroll") for (int bi = 0; bi < 4; ++bi) {                             \
      _Pragma("unroll") for (int kq = 0; kq < KQ; ++kq) {                          \
        const int b = b0w + bi;                                                    \
        const int k = KBASE + kq;                                                  \
        const int u = bi * 4 + kq;                                                 \
        int sidx = dsd1[b * K1N + k];                                              \
        float es = symp[(sidx << 6) | lane];                                       \
        const int* dp = dsd2 + (b * K1N + k) * K2N;                                \
        float acc = 0.f; int c2 = 0;                                               \
        _Pragma("unroll") for (int j = 0; j < K2N; ++j) {                          \
          int dj = dp[j]; c2 += (dj != 0); acc += dise[(dj << 6) | lane];          \
        }                                                                          \
        float ad = acc * nb_w((float)c2);                                          \
        float tt1 = es + ad;                                                       \
        t2r[bi][kq] = es * ad;                                                     \
        c1f += ((g == bi) && (sidx != 0)) ? 1.f : 0.f;                             \
        const int off = u * 64 + (((lane >> 3) ^ (u & 7)) << 3) + (lane & 7);      \
        unsigned short hh = f2bf(tt1);                                             \
        x0[off] = hh;                                                              \
        x1p[off] = f2bf(tt1 - bf2f(hh));                                           \
      }                                                                            \
    }                                                                              \
    asm volatile("s_waitcnt lgkmcnt(0)" ::: "memory");                             \
    f32x4 acc4[4];                                                                 \
    _Pragma("unroll") for (int nt = 0; nt < 4; ++nt)                               \
      acc4[nt] = (f32x4){0.f, 0.f, 0.f, 0.f};                                      \
    short8 ah[2], al[2];                                                           \
    _Pragma("unroll") for (int ks = 0; ks < 2; ++ks) {                             \
      const int aoff = r15 * 64 + (((4 * ks + g) ^ (r15 & 7)) << 3);               \
      ah[ks] = *reinterpret_cast<const short8*>(x0 + aoff);                        \
      al[ks] = *reinterpret_cast<const short8*>(x1p + aoff);                       \
    }                                                                              \
    _Pragma("unroll") for (int ks = 0; ks < 2; ++ks)                               \
      _Pragma("unroll") for (int nt = 0; nt < 4; ++nt) {                           \
        const int wb = (nt * 16 + r15) * 64 + (((4 * ks + g) ^ (r15 & 7)) << 3);   \
        short8 w21l = *reinterpret_cast<const short8*>(&Wl[0][wb]);                \
        acc4[nt] = __builtin_amdgcn_mfma_f32_16x16x32_bf16(ah[ks], Bh[nt][ks], acc4[nt], 0, 0, 0); \
        acc4[nt] = __builtin_amdgcn_mfma_f32_16x16x32_bf16(al[ks], Bh[nt][ks], acc4[nt], 0, 0, 0); \
        acc4[nt] = __builtin_amdgcn_mfma_f32_16x16x32_bf16(ah[ks], w21l, acc4[nt], 0, 0, 0); \
      }                                                                            \
    asm volatile("s_waitcnt lgkmcnt(0)" ::: "memory"); /* A-reads landed */        \
    _Pragma("unroll") for (int bi = 0; bi < 4; ++bi)                               \
      _Pragma("unroll") for (int kq = 0; kq < KQ; ++kq) {                          \
        const int u = bi * 4 + kq;                                                 \
        const int off = u * 64 + (((lane >> 3) ^ (u & 7)) << 3) + (lane & 7);      \
        unsigned short hh = f2bf(t2r[bi][kq]);                                     \
        x0[off] = hh;                                                              \
        x1p[off] = f2bf(t2r[bi][kq] - bf2f(hh));                                   \
      }                                                                            \
    asm volatile("s_waitcnt lgkmcnt(0)" ::: "memory");                             \
    _Pragma("unroll") for (int ks = 0; ks < 2; ++ks) {                             \
      const int aoff = r15 * 64 + (((4 * ks + g) ^ (r15 & 7)) << 3);               \
      ah[ks] = *reinterpret_cast<const short8*>(x0 + aoff);                        \
      al[ks] = *reinterpret_cast<const short8*>(x1p + aoff);                       \
    }                                                                              \
    _Pragma("unroll") for (int ks = 0; ks < 2; ++ks)                               \
      _Pragma("unroll") for (int nt = 0; nt < 4; ++nt) {                           \
        const int wb = (nt * 16 + r15) * 64 + (((4 * ks + g) ^ (r15 & 7)) << 3);   \
        short8 w22h = *reinterpret_cast<const short8*>(&Wl[1][wb]);                \
        short8 w22l = *reinterpret_cast<const short8*>(&Wl[2][wb]);                \
        acc4[nt] = __builtin_amdgcn_mfma_f32_16x16x32_bf16(ah[ks], w22h, acc4[nt], 0, 0, 0); \
        acc4[nt] = __builtin_amdgcn_mfma_f32_16x16x32_bf16(al[ks], w22h, acc4[nt], 0, 0, 0); \
        acc4[nt] = __builtin_amdgcn_mfma_f32_16x16x32_bf16(ah[ks], w22l, acc4[nt], 0, 0, 0); \
      }                                                                            \
    _Pragma("unroll") for (int rr = 0; rr < KQ; ++rr) {                            \
      float ta[4], ss = 0.f;                                                       \
      _Pragma("unroll") for (int nt = 0; nt < 4; ++nt) {                           \
        ta[nt] = fast_tanh(acc4[nt][rr]);                                          \
        ss = fmaf(ta[nt], ta[nt], ss);                                             \
      }                                                                            \
      ss += __shfl_xor(ss, 1, 64); ss += __shfl_xor(ss, 2, 64);                    \
      ss += __shfl_xor(ss, 4, 64); ss += __shfl_xor(ss, 8, 64);                    \
      float inv = __builtin_amdgcn_rcpf(fmaxf(sqrtf(ss), 1e-12f));                 \
      _Pragma("unroll") for (int nt = 0; nt < 4; ++nt)                             \
        s1sum[nt] = fmaf(ta[nt], inv, s1sum[nt]);                                  \
    }                                                                              \
  }

  P1_STEP(0, 4)
  P1_STEP(4, 4)
  P1_STEP(8, 2)
#undef P1_STEP

  // lane's elem is b0w + g; cols d = nt*16 + r15
  float w = nb_w(c1f);
  float* dst = s1avg + (size_t)(b0w + g) * 64 + r15;
#pragma unroll
  for (int nt = 0; nt < 4; ++nt) dst[nt * 16] = s1sum[nt] * w;
}

// ============ fused usu-gather + final: 1 wave = 16 elems, MFMA epilogue ============
// y1 = (s1+t)W11^T + (s1.t)W12^T ; y2 = mu Wu^T ; out = sum_d tanh(y1)tanh(y2)
// W hi-frags in regs (96 VGPR); lo planes in LDS (24KB); X: 6 planes (12KB).
__global__ __launch_bounds__(64, 2) void hgnn_final(
    const int* __restrict__ usu1, const int* __restrict__ label,
    const float* __restrict__ symp, const float* __restrict__ dise,
    const float* __restrict__ W11, const float* __restrict__ W12,
    const float* __restrict__ Wu,
    const float* __restrict__ s1avg, float* __restrict__ out) {
  __shared__ unsigned short Wl[3][4096];    // {w11lo, w12lo, wulo}
  __shared__ unsigned short Xs[6][1024];    // {x1h,x1l,x2h,x2l,x3h,x3l}
  const int lane = threadIdx.x;
  const int g = lane >> 4, r15 = lane & 15;

  // ---- stage 3 lo-planes: 1536 chunks / 64 lanes = 24 iters ----
#pragma unroll 4
  for (int i = 0; i < 24; ++i) {
    int c = lane + (i << 6);
    int pl = c >> 9;
    int rc = c & 511;
    int row = rc >> 3, ch = rc & 7;
    const float* mat = (pl == 0) ? W11 : (pl == 1) ? W12 : Wu;
    const float* src = mat + row * 64 + ch * 8;
    short8 v;
#pragma unroll
    for (int j = 0; j < 8; ++j) {
      float w = src[j];
      v[j] = (short)f2bf(w - bf2f(f2bf(w)));
    }
    *reinterpret_cast<short8*>(&Wl[pl][row * 64 + ((ch ^ (row & 7)) << 3)]) = v;
  }
  // ---- hi B-frags of W11/W12/Wu into 96 VGPRs ----
  short8 Bh[3][4][2];
#pragma unroll
  for (int mt = 0; mt < 3; ++mt) {
    const float* Wm = (mt == 0) ? W11 : (mt == 1) ? W12 : Wu;
#pragma unroll
    for (int nt = 0; nt < 4; ++nt)
#pragma unroll
      for (int ks = 0; ks < 2; ++ks) {
        const float4* p = reinterpret_cast<const float4*>(Wm + (nt * 16 + r15) * 64 + ks * 32 + g * 8);
        float4 va = p[0], vb = p[1];
        short8 h;
        h[0] = (short)f2bf(va.x); h[1] = (short)f2bf(va.y);
        h[2] = (short)f2bf(va.z); h[3] = (short)f2bf(va.w);
        h[4] = (short)f2bf(vb.x); h[5] = (short)f2bf(vb.y);
        h[6] = (short)f2bf(vb.z); h[7] = (short)f2bf(vb.w);
        Bh[mt][nt][ks] = h;
      }
  }
  __syncthreads();

  const int b0w = blockIdx.x * 16;
  // ---- gather + X writes: 16 elems, 50-deep usu gather each ----
#pragma unroll 2
  for (int e = 0; e < 16; ++e) {
    const int b = b0w + e;
    int lb = label[b];
    float t = dise[(lb << 6) | lane];
    float s1 = s1avg[(size_t)b * 64 + lane];
    const int* up = usu1 + b * MMN;
    float su = 0.f; int cu = 0;
#pragma unroll
    for (int m = 0; m < MMN; ++m) {
      int ui = up[m];
      cu += (ui != 0);
      su += symp[(ui << 6) | lane];   // symp row 0 is exactly zero
    }
    float x1 = s1 + t, x2 = s1 * t, x3 = su * nb_w((float)cu);
    const int off = e * 64 + (((lane >> 3) ^ (e & 7)) << 3) + (lane & 7);
    unsigned short hh;
    hh = f2bf(x1); Xs[0][off] = hh; Xs[1][off] = f2bf(x1 - bf2f(hh));
    hh = f2bf(x2); Xs[2][off] = hh; Xs[3][off] = f2bf(x2 - bf2f(hh));
    hh = f2bf(x3); Xs[4][off] = hh; Xs[5][off] = f2bf(x3 - bf2f(hh));
  }
  asm volatile("s_waitcnt lgkmcnt(0)" ::: "memory");

  f32x4 y1[4], y2[4];
#pragma unroll
  for (int nt = 0; nt < 4; ++nt) {
    y1[nt] = (f32x4){0.f, 0.f, 0.f, 0.f};
    y2[nt] = (f32x4){0.f, 0.f, 0.f, 0.f};
  }
#pragma unroll
  for (int ks = 0; ks < 2; ++ks) {
    const int aoff = r15 * 64 + (((4 * ks + g) ^ (r15 & 7)) << 3);
    short8 a1h = *reinterpret_cast<const short8*>(&Xs[0][aoff]);
    short8 a1l = *reinterpret_cast<const short8*>(&Xs[1][aoff]);
    short8 a2h = *reinterpret_cast<const short8*>(&Xs[2][aoff]);
    short8 a2l = *reinterpret_cast<const short8*>(&Xs[3][aoff]);
    short8 a3h = *reinterpret_cast<const short8*>(&Xs[4][aoff]);
    short8 a3l = *reinterpret_cast<const short8*>(&Xs[5][aoff]);
#pragma unroll
    for (int nt = 0; nt < 4; ++nt) {
      const int wb = (nt * 16 + r15) * 64 + (((4 * ks + g) ^ (r15 & 7)) << 3);
      short8 w11l = *reinterpret_cast<const short8*>(&Wl[0][wb]);
      short8 w12l = *reinterpret_cast<const short8*>(&Wl[1][wb]);
      short8 wul = *reinterpret_cast<const short8*>(&Wl[2][wb]);
      y1[nt] = __builtin_amdgcn_mfma_f32_16x16x32_bf16(a1h, Bh[0][nt][ks], y1[nt], 0, 0, 0);
      y1[nt] = __builtin_amdgcn_mfma_f32_16x16x32_bf16(a1l, Bh[0][nt][ks], y1[nt], 0, 0, 0);
      y1[nt] = __builtin_amdgcn_mfma_f32_16x16x32_bf16(a1h, w11l, y1[nt], 0, 0, 0);
      y1[nt] = __builtin_amdgcn_mfma_f32_16x16x32_bf16(a2h, Bh[1][nt][ks], y1[nt], 0, 0, 0);
      y1[nt] = __builtin_amdgcn_mfma_f32_16x16x32_bf16(a2l, Bh[1][nt][ks], y1[nt], 0, 0, 0);
      y1[nt] = __builtin_amdgcn_mfma_f32_16x16x32_bf16(a2h, w12l, y1[nt], 0, 0, 0);
      y2[nt] = __builtin_amdgcn_mfma_f32_16x16x32_bf16(a3h, Bh[2][nt][ks], y2[nt], 0, 0, 0);
      y2[nt] = __builtin_amdgcn_mfma_f32_16x16x32_bf16(a3l, Bh[2][nt][ks], y2[nt], 0, 0, 0);
      y2[nt] = __builtin_amdgcn_mfma_f32_16x16x32_bf16(a3h, wul, y2[nt], 0, 0, 0);
    }
  }
#pragma unroll
  for (int rr = 0; rr < 4; ++rr) {
    float dp = 0.f;
#pragma unroll
    for (int nt = 0; nt < 4; ++nt)
      dp = fmaf(fast_tanh(y1[nt][rr]), fast_tanh(y2[nt][rr]), dp);
    dp += __shfl_xor(dp, 1, 64); dp += __shfl_xor(dp, 2, 64);
    dp += __shfl_xor(dp, 4, 64); dp += __shfl_xor(dp, 8, 64);
    if (r15 == 0) out[b0w + 4 * g + rr] = dp;
  }
}

extern "C" void kernel_launch(void* const* d_in, const int* in_sizes, int n_in,
                              void* d_out, int out_size, void* d_ws, size_t ws_size,
                              hipStream_t stream) {
  const int* dsd1 = (const int*)d_in[0];
  const int* dsd2 = (const int*)d_in[1];
  const int* usu1 = (const int*)d_in[2];
  const int* label = (const int*)d_in[3];
  const float* symp = (const float*)d_in[4];
  const float* dise = (const float*)d_in[5];
  const float* Wu = (const float*)d_in[6];
  const float* W21 = (const float*)d_in[7];
  const float* W22 = (const float*)d_in[8];
  const float* W11 = (const float*)d_in[9];
  const float* W12 = (const float*)d_in[10];
  float* out = (float*)d_out;

  const int B = in_sizes[3];
  float* s1 = (float*)d_ws;  // B*64 f32 = 4 MB

  hipLaunchKernelGGL(hgnn_phase1, dim3(B / 16), dim3(256), 0, stream,
                     dsd1, dsd2, symp, dise, W21, W22, s1);
  hipLaunchKernelGGL(hgnn_final, dim3(B / 16), dim3(64), 0, stream,
                     usu1, label, symp, dise, W11, W12, Wu, s1, out);
}

// Round 5
// 325.845 us; speedup vs baseline: 1.0114x; 1.0114x over previous
//
#include <hip/hip_runtime.h>

#define K1N 10
#define K2N 10
#define MMN 50

typedef __attribute__((ext_vector_type(8))) short short8;
typedef __attribute__((ext_vector_type(4))) float f32x4;

__device__ __forceinline__ float fast_tanh(float x) {
  x = fminf(fmaxf(x, -15.f), 15.f);
  float e2 = __expf(2.f * x);
  return (e2 - 1.f) * __builtin_amdgcn_rcpf(e2 + 1.f);
}

// f32 -> bf16 RNE as raw ushort; exact bf16 -> f32
__device__ __forceinline__ unsigned short f2bf(float x) {
  unsigned u = __builtin_bit_cast(unsigned, x);
  return (unsigned short)((u + 0x7FFFu + ((u >> 16) & 1u)) >> 16);
}
__device__ __forceinline__ float bf2f(unsigned short s) {
  return __builtin_bit_cast(float, ((unsigned)s) << 16);
}

__device__ __forceinline__ void fma4(float& y, float4 w, float4 x) {
  y = fmaf(w.x, x.x, y);
  y = fmaf(w.y, x.y, y);
  y = fmaf(w.z, x.z, y);
  y = fmaf(w.w, x.w, y);
}

// stage 64x64 f32 into LDS, XOR-swizzled float4 chunks (final kernel)
__device__ __forceinline__ void stage_w(const float* __restrict__ W, float* lds, int tid) {
  const float4* src = reinterpret_cast<const float4*>(W);
  float4* dst = reinterpret_cast<float4*>(lds);
#pragma unroll
  for (int i = 0; i < 4; ++i) {
    int c = tid + i * 256;
    int e = c >> 4, q = c & 15;
    dst[(e << 4) | (q ^ (e & 7))] = src[c];
  }
}

#define MFMA16(A, B, C) __builtin_amdgcn_mfma_f32_16x16x32_bf16(A, B, C, 0, 0, 0)

// one phase-1 step: KQ k-values per elem (rows u=bi*4+kq), MQ usu loads per elem.
template <int KQ, int MQ>
__device__ __forceinline__ void p1_step(
    int kbase, int m0, int b0w, int lane, int g, int r15,
    const int* __restrict__ dsd1, const int* __restrict__ dsd2,
    const int* __restrict__ usu1,
    const float* __restrict__ symp, const float* __restrict__ dise,
    const float* Wtab, const unsigned short* Wl0, const unsigned short* Wl1,
    unsigned short* x0, unsigned short* x1, unsigned short* x2, unsigned short* x3,
    const short8 (&Bh)[2][4][2],
    float (&s1sum)[4], float (&su)[4], float (&cuf)[4], float& c1f) {
  // ---- gather + single-pass X plane writes + usu chunk ----
#pragma unroll
  for (int bi = 0; bi < 4; ++bi) {
    const int b = b0w + bi;
#pragma unroll
    for (int kq = 0; kq < KQ; ++kq) {
      const int u = bi * 4 + kq;
      const int k = kbase + kq;
      int sidx = dsd1[b * K1N + k];
      float es = symp[(sidx << 6) | lane];
      const int* dp = dsd2 + (b * K1N + k) * K2N;
      float acc = 0.f;
      int c2 = 0;
#pragma unroll
      for (int j = 0; j < K2N; ++j) {
        int dj = dp[j];
        c2 += (dj != 0);
        acc += dise[(dj << 6) | lane];  // dise row 0 is exactly zero
      }
      float ad = acc * Wtab[c2];        // exact-div table, LDS broadcast
      float t1 = es + ad, t2 = es * ad;
      c1f += ((g == bi) && (sidx != 0)) ? 1.f : 0.f;
      const int off = u * 64 + (((lane >> 3) ^ (u & 7)) << 3) + (lane & 7);
      unsigned short hh;
      hh = f2bf(t1); x0[off] = hh; x1[off] = f2bf(t1 - bf2f(hh));
      hh = f2bf(t2); x2[off] = hh; x3[off] = f2bf(t2 - bf2f(hh));
    }
    // fused usu gather chunk (pure streaming, hides under latency stalls)
    const int* up = usu1 + b * MMN + m0;
#pragma unroll
    for (int m = 0; m < MQ; ++m) {
      int ui = up[m];
      cuf[bi] += (ui != 0) ? 1.f : 0.f;
      su[bi] += symp[(ui << 6) | lane];  // symp row 0 is exactly zero
    }
  }
  asm volatile("s_waitcnt lgkmcnt(0)" ::: "memory");  // X writes visible to own-wave reads

  // ---- MFMA: Y = X1*W21^T + X2*W22^T, 3-term bf16 split each ----
  f32x4 acc4[4];
#pragma unroll
  for (int nt = 0; nt < 4; ++nt) acc4[nt] = (f32x4){0.f, 0.f, 0.f, 0.f};
#pragma unroll
  for (int ks = 0; ks < 2; ++ks) {
    const int aoff = r15 * 64 + (((4 * ks + g) ^ (r15 & 7)) << 3);
    short8 a1h = *reinterpret_cast<const short8*>(x0 + aoff);
    short8 a1l = *reinterpret_cast<const short8*>(x1 + aoff);
    short8 a2h = *reinterpret_cast<const short8*>(x2 + aoff);
    short8 a2l = *reinterpret_cast<const short8*>(x3 + aoff);
#pragma unroll
    for (int nt = 0; nt < 4; ++nt) {
      const int wb = (nt * 16 + r15) * 64 + (((4 * ks + g) ^ (r15 & 7)) << 3);
      short8 w21l = *reinterpret_cast<const short8*>(Wl0 + wb);
      short8 w22l = *reinterpret_cast<const short8*>(Wl1 + wb);
      acc4[nt] = MFMA16(a1h, Bh[0][nt][ks], acc4[nt]);
      acc4[nt] = MFMA16(a1l, Bh[0][nt][ks], acc4[nt]);
      acc4[nt] = MFMA16(a1h, w21l, acc4[nt]);
      acc4[nt] = MFMA16(a2h, Bh[1][nt][ks], acc4[nt]);
      acc4[nt] = MFMA16(a2l, Bh[1][nt][ks], acc4[nt]);
      acc4[nt] = MFMA16(a2h, w22l, acc4[nt]);
    }
  }
  // ---- epilogue: tanh + l2norm per valid row (row 4g+rr = elem g, kq=rr) ----
#pragma unroll
  for (int rr = 0; rr < KQ; ++rr) {
    float ta[4], ss = 0.f;
#pragma unroll
    for (int nt = 0; nt < 4; ++nt) {
      ta[nt] = fast_tanh(acc4[nt][rr]);
      ss = fmaf(ta[nt], ta[nt], ss);
    }
    ss += __shfl_xor(ss, 1, 64); ss += __shfl_xor(ss, 2, 64);
    ss += __shfl_xor(ss, 4, 64); ss += __shfl_xor(ss, 8, 64);
    float inv = __builtin_amdgcn_rcpf(fmaxf(sqrtf(ss), 1e-12f));
#pragma unroll
    for (int nt = 0; nt < 4; ++nt) s1sum[nt] = fmaf(ta[nt], inv, s1sum[nt]);
  }
}

// ============ phase 1 (+fused usu): block = 4 waves, wave = 4 elems ============
__global__ __launch_bounds__(256, 3) void hgnn_phase1(
    const int* __restrict__ dsd1, const int* __restrict__ dsd2,
    const int* __restrict__ usu1,
    const float* __restrict__ symp, const float* __restrict__ dise,
    const float* __restrict__ W21, const float* __restrict__ W22,
    float* __restrict__ s1avg, float* __restrict__ mu) {
  __shared__ unsigned short Wl[2][4096];     // {w21lo, w22lo} swizzled bf16 planes (16 KB)
  __shared__ unsigned short Xs[4][4][1024];  // per-wave {t1h,t1l,t2h,t2l} (32 KB)
  __shared__ float Wtab[64];                 // exact 1/(c+1e-8) table
  const int tid = threadIdx.x;
  const int lane = tid & 63;
  const int wv = __builtin_amdgcn_readfirstlane(tid >> 6);
  const int g = lane >> 4, r15 = lane & 15;

  if (tid < 64) {
    float w = 1.0f / ((float)tid + 1e-8f);
    Wtab[tid] = (w >= 1e8f) ? 0.f : w;
  }
  // stage W lo planes: 1024 16B-chunks, 4/thread
#pragma unroll
  for (int i = 0; i < 4; ++i) {
    int c = tid + (i << 8);
    int pl = c >> 9;
    int rc = c & 511;
    int row = rc >> 3, ch = rc & 7;
    const float* src = (pl ? W22 : W21) + row * 64 + ch * 8;
    short8 v;
#pragma unroll
    for (int j = 0; j < 8; ++j) {
      float w = src[j];
      v[j] = (short)f2bf(w - bf2f(f2bf(w)));
    }
    *reinterpret_cast<short8*>(&Wl[pl][row * 64 + ((ch ^ (row & 7)) << 3)]) = v;
  }
  // W21/W22 hi B-frags into 64 VGPRs
  short8 Bh[2][4][2];
#pragma unroll
  for (int mat = 0; mat < 2; ++mat) {
    const float* Wm = mat ? W22 : W21;
#pragma unroll
    for (int nt = 0; nt < 4; ++nt)
#pragma unroll
      for (int ks = 0; ks < 2; ++ks) {
        const float4* p = reinterpret_cast<const float4*>(Wm + (nt * 16 + r15) * 64 + ks * 32 + g * 8);
        float4 va = p[0], vb = p[1];
        short8 h;
        h[0] = (short)f2bf(va.x); h[1] = (short)f2bf(va.y);
        h[2] = (short)f2bf(va.z); h[3] = (short)f2bf(va.w);
        h[4] = (short)f2bf(vb.x); h[5] = (short)f2bf(vb.y);
        h[6] = (short)f2bf(vb.z); h[7] = (short)f2bf(vb.w);
        Bh[mat][nt][ks] = h;
      }
  }
  __syncthreads();

  const int b0w = blockIdx.x * 16 + wv * 4;
  unsigned short* x0 = &Xs[wv][0][0];
  unsigned short* x1 = &Xs[wv][1][0];
  unsigned short* x2 = &Xs[wv][2][0];
  unsigned short* x3 = &Xs[wv][3][0];
  float s1sum[4] = {0.f, 0.f, 0.f, 0.f};
  float su[4] = {0.f, 0.f, 0.f, 0.f};
  float cuf[4] = {0.f, 0.f, 0.f, 0.f};
  float c1f = 0.f;

  p1_step<4, 17>(0, 0, b0w, lane, g, r15, dsd1, dsd2, usu1, symp, dise,
                 Wtab, Wl[0], Wl[1], x0, x1, x2, x3, Bh, s1sum, su, cuf, c1f);
  p1_step<4, 17>(4, 17, b0w, lane, g, r15, dsd1, dsd2, usu1, symp, dise,
                 Wtab, Wl[0], Wl[1], x0, x1, x2, x3, Bh, s1sum, su, cuf, c1f);
  p1_step<2, 16>(8, 34, b0w, lane, g, r15, dsd1, dsd2, usu1, symp, dise,
                 Wtab, Wl[0], Wl[1], x0, x1, x2, x3, Bh, s1sum, su, cuf, c1f);

  // s1avg for lane's elem (b0w+g), cols d = nt*16 + r15
  float w1 = Wtab[(int)c1f];
  float* dst = s1avg + (size_t)(b0w + g) * 64 + r15;
#pragma unroll
  for (int nt = 0; nt < 4; ++nt) dst[nt * 16] = s1sum[nt] * w1;
  // mu for all 4 elems (lane = d)
#pragma unroll
  for (int bi = 0; bi < 4; ++bi)
    mu[(size_t)(b0w + bi) * 64 + lane] = su[bi] * Wtab[(int)cuf[bi]];
}

// ================= final: label gather + 3 matvecs + dot (proven round-3 kernel) =================
__global__ __launch_bounds__(256, 2) void hgnn_final(
    const int* __restrict__ label, const float* __restrict__ dise,
    const float* __restrict__ W11, const float* __restrict__ W12,
    const float* __restrict__ Wu,
    const float* __restrict__ s1avg, const float* __restrict__ mu,
    float* __restrict__ out) {
  __shared__ float lw[3][4096];
  __shared__ float xb[4][4][3][64];
  const int tid = threadIdx.x;
  const int lane = tid & 63;
  const int wv = __builtin_amdgcn_readfirstlane(tid >> 6);
  stage_w(W11, lw[0], tid);
  stage_w(W12, lw[1], tid);
  stage_w(Wu, lw[2], tid);
  __syncthreads();

  const int b0 = blockIdx.x * 16 + wv * 4;
#pragma unroll
  for (int bi = 0; bi < 4; ++bi) {
    const int b = b0 + bi;
    float s1 = s1avg[(size_t)b * 64 + lane];
    float mv = mu[(size_t)b * 64 + lane];
    int lb = label[b];
    float t = dise[(lb << 6) | lane];
    xb[wv][bi][0][lane] = s1 + t;
    xb[wv][bi][1][lane] = s1 * t;
    xb[wv][bi][2][lane] = mv;
  }
  asm volatile("s_waitcnt lgkmcnt(0)" ::: "memory");

  float y1[4] = {0.f, 0.f, 0.f, 0.f};
  float y2[4] = {0.f, 0.f, 0.f, 0.f};
  const int swz = lane & 7;
#pragma unroll 4
  for (int q = 0; q < 16; ++q) {
    float4 wa = reinterpret_cast<float4*>(lw[0])[(lane << 4) | (q ^ swz)];
    float4 wb = reinterpret_cast<float4*>(lw[1])[(lane << 4) | (q ^ swz)];
    float4 wc = reinterpret_cast<float4*>(lw[2])[(lane << 4) | (q ^ swz)];
#pragma unroll
    for (int bi = 0; bi < 4; ++bi) {
      float4 xv1 = *reinterpret_cast<const float4*>(&xb[wv][bi][0][q << 2]);
      float4 xv2 = *reinterpret_cast<const float4*>(&xb[wv][bi][1][q << 2]);
      float4 xv3 = *reinterpret_cast<const float4*>(&xb[wv][bi][2][q << 2]);
      fma4(y1[bi], wa, xv1);
      fma4(y1[bi], wb, xv2);
      fma4(y2[bi], wc, xv3);
    }
  }
#pragma unroll
  for (int bi = 0; bi < 4; ++bi) {
    float ed = fast_tanh(y1[bi]);
    float eu = fast_tanh(y2[bi]);
    float p = ed * eu;
#pragma unroll
    for (int off = 32; off; off >>= 1) p += __shfl_xor(p, off, 64);
    if (lane == 0) out[b0 + bi] = p;
  }
}

extern "C" void kernel_launch(void* const* d_in, const int* in_sizes, int n_in,
                              void* d_out, int out_size, void* d_ws, size_t ws_size,
                              hipStream_t stream) {
  const int* dsd1 = (const int*)d_in[0];
  const int* dsd2 = (const int*)d_in[1];
  const int* usu1 = (const int*)d_in[2];
  const int* label = (const int*)d_in[3];
  const float* symp = (const float*)d_in[4];
  const float* dise = (const float*)d_in[5];
  const float* Wu = (const float*)d_in[6];
  const float* W21 = (const float*)d_in[7];
  const float* W22 = (const float*)d_in[8];
  const float* W11 = (const float*)d_in[9];
  const float* W12 = (const float*)d_in[10];
  float* out = (float*)d_out;

  const int B = in_sizes[3];
  float* s1 = (float*)d_ws;        // B*64 f32 = 4 MB
  float* mu = s1 + (size_t)B * 64; // B*64 f32 = 4 MB

  hipLaunchKernelGGL(hgnn_phase1, dim3(B / 16), dim3(256), 0, stream,
                     dsd1, dsd2, usu1, symp, dise, W21, W22, s1, mu);
  hipLaunchKernelGGL(hgnn_final, dim3(B / 16), dim3(256), 0, stream,
                     label, dise, W11, W12, Wu, s1, mu, out);
}

// Round 6
// 201.432 us; speedup vs baseline: 1.6360x; 1.6176x over previous
//
#include <hip/hip_runtime.h>

#define K1N 10
#define K2N 10
#define MMN 50

typedef __attribute__((ext_vector_type(8))) short short8;
typedef __attribute__((ext_vector_type(4))) float f32x4;

__device__ __forceinline__ float fast_tanh(float x) {
  x = fminf(fmaxf(x, -15.f), 15.f);
  float e2 = __expf(2.f * x);
  return (e2 - 1.f) * __builtin_amdgcn_rcpf(e2 + 1.f);
}

// reference's _avg_on_real_neighbor weight (exact f32 semantics)
__device__ __forceinline__ float nb_w(float cnt) {
  float w = 1.0f / (cnt + 1e-8f);
  return (w >= 1e8f) ? 0.f : w;
}

// f32 -> bf16 RNE as raw ushort; exact bf16 -> f32
__device__ __forceinline__ unsigned short f2bf(float x) {
  unsigned u = __builtin_bit_cast(unsigned, x);
  return (unsigned short)((u + 0x7FFFu + ((u >> 16) & 1u)) >> 16);
}
__device__ __forceinline__ float bf2f(unsigned short s) {
  return __builtin_bit_cast(float, ((unsigned)s) << 16);
}

__device__ __forceinline__ void fma4(float& y, float4 w, float4 x) {
  y = fmaf(w.x, x.x, y);
  y = fmaf(w.y, x.y, y);
  y = fmaf(w.z, x.z, y);
  y = fmaf(w.w, x.w, y);
}

// stage 64x64 f32 into LDS, XOR-swizzled float4 chunks (final kernel)
__device__ __forceinline__ void stage_w(const float* __restrict__ W, float* lds, int tid) {
  const float4* src = reinterpret_cast<const float4*>(W);
  float4* dst = reinterpret_cast<float4*>(lds);
#pragma unroll
  for (int i = 0; i < 4; ++i) {
    int c = tid + i * 256;
    int e = c >> 4, q = c & 15;
    dst[(e << 4) | (q ^ (e & 7))] = src[c];
  }
}

#define MFMA16(A, B, C) __builtin_amdgcn_mfma_f32_16x16x32_bf16(A, B, C, 0, 0, 0)

// one phase-1 step: 16 MFMA rows = unit u (r15) = (bi = u>>2, kq = u&3), kq < KQ valid.
// Lane (g, r15) gathers dims [8g,8g+8) and [32+8g,32+8g+8) of unit r15 -> A-frags in regs.
template <int KQ>
__device__ __forceinline__ void p1_step(
    int kbase, int b0w, int g, int r15,
    const int* __restrict__ dsd1, const int* __restrict__ dsd2,
    const float* __restrict__ symp, const float* __restrict__ dise,
    const unsigned short* Wl, float (&s1sum)[4], float& c1f) {
  short8 a1h[2], a1l[2], a2h[2], a2l[2];
#pragma unroll
  for (int ks = 0; ks < 2; ++ks)
#pragma unroll
    for (int j = 0; j < 8; ++j) {
      a1h[ks][j] = 0; a1l[ks][j] = 0; a2h[ks][j] = 0; a2l[ks][j] = 0;
    }

  const int kq = r15 & 3, bi = r15 >> 2;
  if (kq < KQ) {
    const int b = b0w + bi;
    const int k = kbase + kq;
    const int sidx = dsd1[b * K1N + k];
    c1f += (sidx != 0) ? 1.f : 0.f;
    const int2* dp = reinterpret_cast<const int2*>(dsd2 + (b * K1N + k) * K2N);
    int2 i01 = dp[0], i23 = dp[1], i45 = dp[2], i67 = dp[3], i89 = dp[4];
    const int idx[10] = {i01.x, i01.y, i23.x, i23.y, i45.x,
                         i45.y, i67.x, i67.y, i89.x, i89.y};
    int c2 = 0;
#pragma unroll
    for (int j = 0; j < 10; ++j) c2 += (idx[j] != 0);
    const int dof = 8 * g;
    const float* sp = symp + (sidx << 6) + dof;
    f32x4 es0 = *(const f32x4*)sp, es1 = *(const f32x4*)(sp + 4);
    f32x4 es2 = *(const f32x4*)(sp + 32), es3 = *(const f32x4*)(sp + 36);
    f32x4 ac0 = {0.f, 0.f, 0.f, 0.f}, ac1 = ac0, ac2 = ac0, ac3 = ac0;
#pragma unroll
    for (int j = 0; j < 10; ++j) {
      const float* rp = dise + (idx[j] << 6) + dof;  // dise row 0 is exactly zero
      ac0 += *(const f32x4*)(rp);
      ac1 += *(const f32x4*)(rp + 4);
      ac2 += *(const f32x4*)(rp + 32);
      ac3 += *(const f32x4*)(rp + 36);
    }
    float w2 = (c2 == 0) ? 0.f : __builtin_amdgcn_rcpf((float)c2 + 1e-8f);
    f32x4 t1[4], t2[4];
    f32x4 ad;
    ad = ac0 * w2; t1[0] = es0 + ad; t2[0] = es0 * ad;
    ad = ac1 * w2; t1[1] = es1 + ad; t2[1] = es1 * ad;
    ad = ac2 * w2; t1[2] = es2 + ad; t2[2] = es2 * ad;
    ad = ac3 * w2; t1[3] = es3 + ad; t2[3] = es3 * ad;
#pragma unroll
    for (int c = 0; c < 4; ++c) {
      const int ks = c >> 1, hb = (c & 1) * 4;
#pragma unroll
      for (int jj = 0; jj < 4; ++jj) {
        float v1 = t1[c][jj], v2 = t2[c][jj];
        unsigned short h1 = f2bf(v1), h2 = f2bf(v2);
        a1h[ks][hb + jj] = (short)h1;
        a1l[ks][hb + jj] = (short)f2bf(v1 - bf2f(h1));
        a2h[ks][hb + jj] = (short)h2;
        a2l[ks][hb + jj] = (short)f2bf(v2 - bf2f(h2));
      }
    }
  }

  // ---- MFMA: Y = X1*W21^T + X2*W22^T, 3-term bf16 split; W planes from LDS ----
  f32x4 acc4[4];
#pragma unroll
  for (int nt = 0; nt < 4; ++nt) acc4[nt] = (f32x4){0.f, 0.f, 0.f, 0.f};
#pragma unroll
  for (int ks = 0; ks < 2; ++ks)
#pragma unroll
    for (int nt = 0; nt < 4; ++nt) {
      const int wb = (nt * 16 + r15) * 64 + (((4 * ks + g) ^ (r15 & 7)) << 3);
      short8 w21h = *(const short8*)(Wl + 0 * 4096 + wb);
      short8 w21l = *(const short8*)(Wl + 1 * 4096 + wb);
      short8 w22h = *(const short8*)(Wl + 2 * 4096 + wb);
      short8 w22l = *(const short8*)(Wl + 3 * 4096 + wb);
      acc4[nt] = MFMA16(a1h[ks], w21h, acc4[nt]);
      acc4[nt] = MFMA16(a1l[ks], w21h, acc4[nt]);
      acc4[nt] = MFMA16(a1h[ks], w21l, acc4[nt]);
      acc4[nt] = MFMA16(a2h[ks], w22h, acc4[nt]);
      acc4[nt] = MFMA16(a2l[ks], w22h, acc4[nt]);
      acc4[nt] = MFMA16(a2h[ks], w22l, acc4[nt]);
    }

  // ---- epilogue: rows 4g+rr all belong to elem g (kq = rr); tanh + l2norm ----
#pragma unroll
  for (int rr = 0; rr < KQ; ++rr) {
    float ta[4], ss = 0.f;
#pragma unroll
    for (int nt = 0; nt < 4; ++nt) {
      ta[nt] = fast_tanh(acc4[nt][rr]);
      ss = fmaf(ta[nt], ta[nt], ss);
    }
    ss += __shfl_xor(ss, 1, 64); ss += __shfl_xor(ss, 2, 64);
    ss += __shfl_xor(ss, 4, 64); ss += __shfl_xor(ss, 8, 64);
    float inv = __builtin_amdgcn_rcpf(fmaxf(sqrtf(ss), 1e-12f));
#pragma unroll
    for (int nt = 0; nt < 4; ++nt) s1sum[nt] = fmaf(ta[nt], inv, s1sum[nt]);
  }
}

// ============ phase 1: block = 4 waves x 4 elems, A-frags built in registers ============
__global__ __launch_bounds__(256, 4) void hgnn_phase1(
    const int* __restrict__ dsd1, const int* __restrict__ dsd2,
    const float* __restrict__ symp, const float* __restrict__ dise,
    const float* __restrict__ W21, const float* __restrict__ W22,
    float* __restrict__ s1avg) {
  __shared__ unsigned short Wl[4 * 4096];  // {w21hi, w21lo, w22hi, w22lo} swizzled (32 KB)
  const int tid = threadIdx.x;
  const int lane = tid & 63;
  const int wv = __builtin_amdgcn_readfirstlane(tid >> 6);
  const int g = lane >> 4, r15 = lane & 15;

  // stage W planes: 2048 16B-chunks, 8/thread
#pragma unroll
  for (int i = 0; i < 8; ++i) {
    int c = tid + (i << 8);
    int pl = c >> 9, rc = c & 511;
    int row = rc >> 3, ch = rc & 7;
    const float* src = ((pl >> 1) ? W22 : W21) + row * 64 + ch * 8;
    const bool lo = pl & 1;
    short8 v;
#pragma unroll
    for (int j = 0; j < 8; ++j) {
      float w = src[j];
      unsigned short h = f2bf(w);
      v[j] = (short)(lo ? f2bf(w - bf2f(h)) : h);
    }
    *reinterpret_cast<short8*>(&Wl[pl * 4096 + row * 64 + ((ch ^ (row & 7)) << 3)]) = v;
  }
  __syncthreads();

  const int b0w = blockIdx.x * 16 + wv * 4;
  float s1sum[4] = {0.f, 0.f, 0.f, 0.f};
  float c1f = 0.f;

  p1_step<4>(0, b0w, g, r15, dsd1, dsd2, symp, dise, Wl, s1sum, c1f);
  p1_step<4>(4, b0w, g, r15, dsd1, dsd2, symp, dise, Wl, s1sum, c1f);
  p1_step<2>(8, b0w, g, r15, dsd1, dsd2, symp, dise, Wl, s1sum, c1f);

  // c1 for elem e is spread over lanes with r15>>2 == e; reduce then fetch elem g's count
  float cc = c1f + __shfl_xor(c1f, 1, 64);
  cc += __shfl_xor(cc, 2, 64);
  const int src = (lane & 48) | (g << 2);  // any lane with r15 = 4g
  float c1 = __shfl(cc, src, 64);
  float w1 = nb_w(c1);

  float* dst = s1avg + (size_t)(b0w + g) * 64 + r15;
#pragma unroll
  for (int nt = 0; nt < 4; ++nt) dst[nt * 16] = s1sum[nt] * w1;
}

// ================= usu gather-average (proven round-3 kernel) =================
__global__ __launch_bounds__(256, 8) void hgnn_usu_avg(
    const int* __restrict__ usu1, const float* __restrict__ symp,
    float* __restrict__ mu) {
  const int tid = threadIdx.x;
  const int lane = tid & 63;
  const int wv = __builtin_amdgcn_readfirstlane(tid >> 6);
  const int b = blockIdx.x * 4 + wv;
  const int* up = usu1 + b * MMN;
  float su = 0.f;
  int cu = 0;
#pragma unroll 10
  for (int m = 0; m < MMN; ++m) {
    int ui = up[m];
    cu += (ui != 0);
    su += symp[(ui << 6) | lane];  // symp row 0 is exactly zero
  }
  mu[(size_t)b * 64 + lane] = su * nb_w((float)cu);
}

// ================= final: label gather + 3 matvecs + dot (proven round-3 kernel) =================
__global__ __launch_bounds__(256, 2) void hgnn_final(
    const int* __restrict__ label, const float* __restrict__ dise,
    const float* __restrict__ W11, const float* __restrict__ W12,
    const float* __restrict__ Wu,
    const float* __restrict__ s1avg, const float* __restrict__ mu,
    float* __restrict__ out) {
  __shared__ float lw[3][4096];
  __shared__ float xb[4][4][3][64];
  const int tid = threadIdx.x;
  const int lane = tid & 63;
  const int wv = __builtin_amdgcn_readfirstlane(tid >> 6);
  stage_w(W11, lw[0], tid);
  stage_w(W12, lw[1], tid);
  stage_w(Wu, lw[2], tid);
  __syncthreads();

  const int b0 = blockIdx.x * 16 + wv * 4;
#pragma unroll
  for (int bi = 0; bi < 4; ++bi) {
    const int b = b0 + bi;
    float s1 = s1avg[(size_t)b * 64 + lane];
    float mv = mu[(size_t)b * 64 + lane];
    int lb = label[b];
    float t = dise[(lb << 6) | lane];
    xb[wv][bi][0][lane] = s1 + t;
    xb[wv][bi][1][lane] = s1 * t;
    xb[wv][bi][2][lane] = mv;
  }
  asm volatile("s_waitcnt lgkmcnt(0)" ::: "memory");

  float y1[4] = {0.f, 0.f, 0.f, 0.f};
  float y2[4] = {0.f, 0.f, 0.f, 0.f};
  const int swz = lane & 7;
#pragma unroll 4
  for (int q = 0; q < 16; ++q) {
    float4 wa = reinterpret_cast<float4*>(lw[0])[(lane << 4) | (q ^ swz)];
    float4 wb = reinterpret_cast<float4*>(lw[1])[(lane << 4) | (q ^ swz)];
    float4 wc = reinterpret_cast<float4*>(lw[2])[(lane << 4) | (q ^ swz)];
#pragma unroll
    for (int bi = 0; bi < 4; ++bi) {
      float4 xv1 = *reinterpret_cast<const float4*>(&xb[wv][bi][0][q << 2]);
      float4 xv2 = *reinterpret_cast<const float4*>(&xb[wv][bi][1][q << 2]);
      float4 xv3 = *reinterpret_cast<const float4*>(&xb[wv][bi][2][q << 2]);
      fma4(y1[bi], wa, xv1);
      fma4(y1[bi], wb, xv2);
      fma4(y2[bi], wc, xv3);
    }
  }
#pragma unroll
  for (int bi = 0; bi < 4; ++bi) {
    float ed = fast_tanh(y1[bi]);
    float eu = fast_tanh(y2[bi]);
    float p = ed * eu;
#pragma unroll
    for (int off = 32; off; off >>= 1) p += __shfl_xor(p, off, 64);
    if (lane == 0) out[b0 + bi] = p;
  }
}

extern "C" void kernel_launch(void* const* d_in, const int* in_sizes, int n_in,
                              void* d_out, int out_size, void* d_ws, size_t ws_size,
                              hipStream_t stream) {
  const int* dsd1 = (const int*)d_in[0];
  const int* dsd2 = (const int*)d_in[1];
  const int* usu1 = (const int*)d_in[2];
  const int* label = (const int*)d_in[3];
  const float* symp = (const float*)d_in[4];
  const float* dise = (const float*)d_in[5];
  const float* Wu = (const float*)d_in[6];
  const float* W21 = (const float*)d_in[7];
  const float* W22 = (const float*)d_in[8];
  const float* W11 = (const float*)d_in[9];
  const float* W12 = (const float*)d_in[10];
  float* out = (float*)d_out;

  const int B = in_sizes[3];
  float* s1 = (float*)d_ws;         // B*64 f32 = 4 MB
  float* mu = s1 + (size_t)B * 64;  // B*64 f32 = 4 MB

  hipLaunchKernelGGL(hgnn_phase1, dim3(B / 16), dim3(256), 0, stream,
                     dsd1, dsd2, symp, dise, W21, W22, s1);
  hipLaunchKernelGGL(hgnn_usu_avg, dim3(B / 4), dim3(256), 0, stream,
                     usu1, symp, mu);
  hipLaunchKernelGGL(hgnn_final, dim3(B / 16), dim3(256), 0, stream,
                     label, dise, W11, W12, Wu, s1, mu, out);
}

// Round 7
// 112.709 us; speedup vs baseline: 2.9239x; 1.7872x over previous
//
#include <hip/hip_runtime.h>

#define K1N 10
#define K2N 10
#define MMN 50

typedef __attribute__((ext_vector_type(8))) short short8;
typedef __attribute__((ext_vector_type(4))) float f32x4;

__device__ __forceinline__ float fast_tanh(float x) {
  x = fminf(fmaxf(x, -15.f), 15.f);
  float e2 = __expf(2.f * x);
  return (e2 - 1.f) * __builtin_amdgcn_rcpf(e2 + 1.f);
}

// reference's _avg_on_real_neighbor weight (exact f32 semantics)
__device__ __forceinline__ float nb_w(float cnt) {
  float w = 1.0f / (cnt + 1e-8f);
  return (w >= 1e8f) ? 0.f : w;
}

// f32 -> bf16 RNE as raw ushort; exact bf16 -> f32
__device__ __forceinline__ unsigned short f2bf(float x) {
  unsigned u = __builtin_bit_cast(unsigned, x);
  return (unsigned short)((u + 0x7FFFu + ((u >> 16) & 1u)) >> 16);
}
__device__ __forceinline__ float bf2f(unsigned short s) {
  return __builtin_bit_cast(float, ((unsigned)s) << 16);
}

__device__ __forceinline__ void fma4(float& y, float4 w, float4 x) {
  y = fmaf(w.x, x.x, y);
  y = fmaf(w.y, x.y, y);
  y = fmaf(w.z, x.z, y);
  y = fmaf(w.w, x.w, y);
}

// stage 64x64 f32 into LDS, XOR-swizzled float4 chunks (final kernel)
__device__ __forceinline__ void stage_w(const float* __restrict__ W, float* lds, int tid) {
  const float4* src = reinterpret_cast<const float4*>(W);
  float4* dst = reinterpret_cast<float4*>(lds);
#pragma unroll
  for (int i = 0; i < 4; ++i) {
    int c = tid + i * 256;
    int e = c >> 4, q = c & 15;
    dst[(e << 4) | (q ^ (e & 7))] = src[c];
  }
}

#define MFMA16(A, B, C) __builtin_amdgcn_mfma_f32_16x16x32_bf16(A, B, C, 0, 0, 0)

// one phase-1 k-chunk: 16 MFMA rows, row u = bi*4+kq (bi=u>>2, kq=u&3), kq<KQ valid.
// Wave-wide coalesced gathers (lane = dim), X via per-wave swizzled LDS planes.
template <int KQ>
__device__ __forceinline__ void p1_step(
    int kbase, int b0w, int lane, int g, int r15,
    const int* __restrict__ dsd1, const int* __restrict__ dsd2,
    const float* __restrict__ symp, const float* __restrict__ dise,
    const unsigned short* __restrict__ Wl0, const unsigned short* __restrict__ Wl1,
    unsigned short* xw, const short8 (&Bh)[2][4][2],
    float (&s1sum)[4], float& c1f) {
  // ---- gather + 4-plane X writes (single pass) ----
#pragma unroll
  for (int u = 0; u < 16; ++u) {
    if ((u & 3) >= KQ) continue;
    const int b = b0w + (u >> 2);
    const int k = kbase + (u & 3);
    const int sidx = dsd1[b * K1N + k];         // wave-uniform -> s_load
    float es = symp[(sidx << 6) | lane];        // coalesced full row
    const int* dp = dsd2 + (b * K1N + k) * K2N; // wave-uniform -> s_load
    float acc = 0.f;
    int c2 = 0;
#pragma unroll
    for (int j = 0; j < K2N; ++j) {
      int dj = dp[j];
      c2 += (dj != 0);
      acc += dise[(dj << 6) | lane];            // dise row 0 is exactly zero
    }
    float w2 = (c2 == 0) ? 0.f : __builtin_amdgcn_rcpf((float)c2 + 1e-8f);
    float ad = acc * w2;
    float t1 = es + ad, t2 = es * ad;
    c1f += ((g == (u >> 2)) && (sidx != 0)) ? 1.f : 0.f;
    const int off = u * 64 + (((lane >> 3) ^ (u & 7)) << 3) + (lane & 7);
    unsigned short hh;
    hh = f2bf(t1); xw[off] = hh; xw[1024 + off] = f2bf(t1 - bf2f(hh));
    hh = f2bf(t2); xw[2048 + off] = hh; xw[3072 + off] = f2bf(t2 - bf2f(hh));
  }
  asm volatile("s_waitcnt lgkmcnt(0)" ::: "memory");  // own-wave X writes visible

  // ---- MFMA: Y = X1*W21^T + X2*W22^T, 3-term bf16 split; hi from regs, lo from LDS ----
  f32x4 acc4[4];
#pragma unroll
  for (int nt = 0; nt < 4; ++nt) acc4[nt] = (f32x4){0.f, 0.f, 0.f, 0.f};
#pragma unroll
  for (int ks = 0; ks < 2; ++ks) {
    const int aoff = r15 * 64 + (((4 * ks + g) ^ (r15 & 7)) << 3);
    short8 a1h = *(const short8*)(xw + aoff);
    short8 a1l = *(const short8*)(xw + 1024 + aoff);
    short8 a2h = *(const short8*)(xw + 2048 + aoff);
    short8 a2l = *(const short8*)(xw + 3072 + aoff);
#pragma unroll
    for (int nt = 0; nt < 4; ++nt) {
      const int wb = (nt * 16 + r15) * 64 + (((4 * ks + g) ^ (r15 & 7)) << 3);
      short8 w21l = *(const short8*)(Wl0 + wb);
      short8 w22l = *(const short8*)(Wl1 + wb);
      acc4[nt] = MFMA16(a1h, Bh[0][nt][ks], acc4[nt]);
      acc4[nt] = MFMA16(a1l, Bh[0][nt][ks], acc4[nt]);
      acc4[nt] = MFMA16(a1h, w21l, acc4[nt]);
      acc4[nt] = MFMA16(a2h, Bh[1][nt][ks], acc4[nt]);
      acc4[nt] = MFMA16(a2l, Bh[1][nt][ks], acc4[nt]);
      acc4[nt] = MFMA16(a2h, w22l, acc4[nt]);
    }
  }
  // ---- epilogue: rows 4g+rr belong to elem g (kq=rr); tanh + l2norm ----
#pragma unroll
  for (int rr = 0; rr < KQ; ++rr) {
    float ta[4], ss = 0.f;
#pragma unroll
    for (int nt = 0; nt < 4; ++nt) {
      ta[nt] = fast_tanh(acc4[nt][rr]);
      ss = fmaf(ta[nt], ta[nt], ss);
    }
    ss += __shfl_xor(ss, 1, 64); ss += __shfl_xor(ss, 2, 64);
    ss += __shfl_xor(ss, 4, 64); ss += __shfl_xor(ss, 8, 64);
    float inv = __builtin_amdgcn_rcpf(fmaxf(sqrtf(ss), 1e-12f));
#pragma unroll
    for (int nt = 0; nt < 4; ++nt) s1sum[nt] = fmaf(ta[nt], inv, s1sum[nt]);
  }
}

// ============ phase 1: 4 waves/block, wave = 4 elems, 3 blocks/CU (48 KB LDS) ============
__global__ __launch_bounds__(256, 3) void hgnn_phase1(
    const int* __restrict__ dsd1, const int* __restrict__ dsd2,
    const float* __restrict__ symp, const float* __restrict__ dise,
    const float* __restrict__ W21, const float* __restrict__ W22,
    float* __restrict__ s1avg) {
  __shared__ unsigned short Wl[2][4096];     // {w21lo, w22lo} swizzled bf16 planes (16 KB)
  __shared__ unsigned short Xs[4][4][1024];  // per-wave {t1h,t1l,t2h,t2l} (32 KB)
  const int tid = threadIdx.x;
  const int lane = tid & 63;
  const int wv = __builtin_amdgcn_readfirstlane(tid >> 6);
  const int g = lane >> 4, r15 = lane & 15;

  // stage W lo planes: 1024 16B-chunks, 4/thread
#pragma unroll
  for (int i = 0; i < 4; ++i) {
    int c = tid + (i << 8);
    int pl = c >> 9, rc = c & 511;
    int row = rc >> 3, ch = rc & 7;
    const float* src = (pl ? W22 : W21) + row * 64 + ch * 8;
    short8 v;
#pragma unroll
    for (int j = 0; j < 8; ++j) {
      float w = src[j];
      v[j] = (short)f2bf(w - bf2f(f2bf(w)));
    }
    *reinterpret_cast<short8*>(&Wl[pl][row * 64 + ((ch ^ (row & 7)) << 3)]) = v;
  }
  // W21/W22 hi B-frags into 64 VGPRs
  short8 Bh[2][4][2];
#pragma unroll
  for (int mat = 0; mat < 2; ++mat) {
    const float* Wm = mat ? W22 : W21;
#pragma unroll
    for (int nt = 0; nt < 4; ++nt)
#pragma unroll
      for (int ks = 0; ks < 2; ++ks) {
        const float4* p = reinterpret_cast<const float4*>(Wm + (nt * 16 + r15) * 64 + ks * 32 + g * 8);
        float4 va = p[0], vb = p[1];
        short8 h;
        h[0] = (short)f2bf(va.x); h[1] = (short)f2bf(va.y);
        h[2] = (short)f2bf(va.z); h[3] = (short)f2bf(va.w);
        h[4] = (short)f2bf(vb.x); h[5] = (short)f2bf(vb.y);
        h[6] = (short)f2bf(vb.z); h[7] = (short)f2bf(vb.w);
        Bh[mat][nt][ks] = h;
      }
  }
  __syncthreads();

  const int b0w = blockIdx.x * 16 + wv * 4;
  unsigned short* xw = &Xs[wv][0][0];
  float s1sum[4] = {0.f, 0.f, 0.f, 0.f};
  float c1f = 0.f;

  p1_step<4>(0, b0w, lane, g, r15, dsd1, dsd2, symp, dise, Wl[0], Wl[1], xw, Bh, s1sum, c1f);
  p1_step<4>(4, b0w, lane, g, r15, dsd1, dsd2, symp, dise, Wl[0], Wl[1], xw, Bh, s1sum, c1f);
  p1_step<2>(8, b0w, lane, g, r15, dsd1, dsd2, symp, dise, Wl[0], Wl[1], xw, Bh, s1sum, c1f);

  // c1f is uniform within each g-group; elem = b0w + g, cols d = nt*16 + r15
  float w1 = nb_w(c1f);
  float* dst = s1avg + (size_t)(b0w + g) * 64 + r15;
#pragma unroll
  for (int nt = 0; nt < 4; ++nt) dst[nt * 16] = s1sum[nt] * w1;
}

// ================= usu gather-average (proven round-3 kernel) =================
__global__ __launch_bounds__(256, 8) void hgnn_usu_avg(
    const int* __restrict__ usu1, const float* __restrict__ symp,
    float* __restrict__ mu) {
  const int tid = threadIdx.x;
  const int lane = tid & 63;
  const int wv = __builtin_amdgcn_readfirstlane(tid >> 6);
  const int b = blockIdx.x * 4 + wv;
  const int* up = usu1 + b * MMN;
  float su = 0.f;
  int cu = 0;
#pragma unroll 10
  for (int m = 0; m < MMN; ++m) {
    int ui = up[m];
    cu += (ui != 0);
    su += symp[(ui << 6) | lane];  // symp row 0 is exactly zero
  }
  mu[(size_t)b * 64 + lane] = su * nb_w((float)cu);
}

// ================= final: label gather + 3 matvecs + dot (proven round-3 kernel) =================
__global__ __launch_bounds__(256, 2) void hgnn_final(
    const int* __restrict__ label, const float* __restrict__ dise,
    const float* __restrict__ W11, const float* __restrict__ W12,
    const float* __restrict__ Wu,
    const float* __restrict__ s1avg, const float* __restrict__ mu,
    float* __restrict__ out) {
  __shared__ float lw[3][4096];
  __shared__ float xb[4][4][3][64];
  const int tid = threadIdx.x;
  const int lane = tid & 63;
  const int wv = __builtin_amdgcn_readfirstlane(tid >> 6);
  stage_w(W11, lw[0], tid);
  stage_w(W12, lw[1], tid);
  stage_w(Wu, lw[2], tid);
  __syncthreads();

  const int b0 = blockIdx.x * 16 + wv * 4;
#pragma unroll
  for (int bi = 0; bi < 4; ++bi) {
    const int b = b0 + bi;
    float s1 = s1avg[(size_t)b * 64 + lane];
    float mv = mu[(size_t)b * 64 + lane];
    int lb = label[b];
    float t = dise[(lb << 6) | lane];
    xb[wv][bi][0][lane] = s1 + t;
    xb[wv][bi][1][lane] = s1 * t;
    xb[wv][bi][2][lane] = mv;
  }
  asm volatile("s_waitcnt lgkmcnt(0)" ::: "memory");

  float y1[4] = {0.f, 0.f, 0.f, 0.f};
  float y2[4] = {0.f, 0.f, 0.f, 0.f};
  const int swz = lane & 7;
#pragma unroll 4
  for (int q = 0; q < 16; ++q) {
    float4 wa = reinterpret_cast<float4*>(lw[0])[(lane << 4) | (q ^ swz)];
    float4 wb = reinterpret_cast<float4*>(lw[1])[(lane << 4) | (q ^ swz)];
    float4 wc = reinterpret_cast<float4*>(lw[2])[(lane << 4) | (q ^ swz)];
#pragma unroll
    for (int bi = 0; bi < 4; ++bi) {
      float4 xv1 = *reinterpret_cast<const float4*>(&xb[wv][bi][0][q << 2]);
      float4 xv2 = *reinterpret_cast<const float4*>(&xb[wv][bi][1][q << 2]);
      float4 xv3 = *reinterpret_cast<const float4*>(&xb[wv][bi][2][q << 2]);
      fma4(y1[bi], wa, xv1);
      fma4(y1[bi], wb, xv2);
      fma4(y2[bi], wc, xv3);
    }
  }
#pragma unroll
  for (int bi = 0; bi < 4; ++bi) {
    float ed = fast_tanh(y1[bi]);
    float eu = fast_tanh(y2[bi]);
    float p = ed * eu;
#pragma unroll
    for (int off = 32; off; off >>= 1) p += __shfl_xor(p, off, 64);
    if (lane == 0) out[b0 + bi] = p;
  }
}

extern "C" void kernel_launch(void* const* d_in, const int* in_sizes, int n_in,
                              void* d_out, int out_size, void* d_ws, size_t ws_size,
                              hipStream_t stream) {
  const int* dsd1 = (const int*)d_in[0];
  const int* dsd2 = (const int*)d_in[1];
  const int* usu1 = (const int*)d_in[2];
  const int* label = (const int*)d_in[3];
  const float* symp = (const float*)d_in[4];
  const float* dise = (const float*)d_in[5];
  const float* Wu = (const float*)d_in[6];
  const float* W21 = (const float*)d_in[7];
  const float* W22 = (const float*)d_in[8];
  const float* W11 = (const float*)d_in[9];
  const float* W12 = (const float*)d_in[10];
  float* out = (float*)d_out;

  const int B = in_sizes[3];
  float* s1 = (float*)d_ws;         // B*64 f32 = 4 MB
  float* mu = s1 + (size_t)B * 64;  // B*64 f32 = 4 MB

  hipLaunchKernelGGL(hgnn_phase1, dim3(B / 16), dim3(256), 0, stream,
                     dsd1, dsd2, symp, dise, W21, W22, s1);
  hipLaunchKernelGGL(hgnn_usu_avg, dim3(B / 4), dim3(256), 0, stream,
                     usu1, symp, mu);
  hipLaunchKernelGGL(hgnn_final, dim3(B / 16), dim3(256), 0, stream,
                     label, dise, W11, W12, Wu, s1, mu, out);
}